// Round 11
// baseline (251.351 us; speedup 1.0000x reference)
//
#include <hip/hip_runtime.h>
#include <math.h>

// GCN 2-layer forward on MI355X — round 11:
//  * REVERT r10 deg atomics (regressed rank pass 43->76us): k_deg is back
//  * keep pp_s fused top-scan (no scan3)
//  * NREP 4->8 on the single rank atomic
//  * NEW: k_agg_gemm fuses agg1 (FIXUP+bias+ReLU) -> LDS bf16 tile -> gemm2
//    (W2 hi-only, 32KB LDS) — removes o1 round trip + one launch
#define CH   128
#define CH4  32
#define TPB  256
#define SCANB 1024
#define WIMG 16384       // shorts per (layer,colh) fragment image (32 KB)
#define NREP 8

typedef __attribute__((ext_vector_type(8))) short short8;   // 8 bf16 (4 VGPRs)
typedef __attribute__((ext_vector_type(4))) float floatx4;  // MFMA acc

static __device__ __forceinline__ unsigned short f2bf(float f) {
    unsigned u = __float_as_uint(f);
    return (unsigned short)((u + 0x7fffu + ((u >> 16) & 1u)) >> 16);
}
static __device__ __forceinline__ float bf2f(unsigned short s) {
    return __uint_as_float(((unsigned)s) << 16);
}
static __device__ __forceinline__ float4 bf4_to_f4(ushort4 u) {
    return make_float4(bf2f(u.x), bf2f(u.y), bf2f(u.z), bf2f(u.w));
}

// ---------------------------------------------------------------------------
// k_prep: split W1,W2 into bf16 hi/lo B-fragment images (32 KB per colh).
// ---------------------------------------------------------------------------
__global__ void k_prep(const float* __restrict__ W1, const float* __restrict__ W2,
                       short* __restrict__ Wsplit) {
    int i = blockIdx.x * blockDim.x + threadIdx.x;   // over 2*128*128
    if (i >= 2 * CH * CH) return;
    int layer = i >> 14;
    int idx   = i & 16383;
    int k = idx >> 7, c = idx & 127;
    float w = (layer ? W2 : W1)[k * CH + c];
    unsigned short hi = f2bf(w);
    unsigned short lo = f2bf(w - bf2f(hi));
    int colh = c >> 6, nn = c & 63;
    int kt = k >> 5, q = (k & 31) >> 3, j = k & 7;
    int ns = nn >> 4, ln = q * 16 + (nn & 15);
    size_t base = (size_t)(layer * 2 + colh) * WIMG;
    size_t off  = ((size_t)(kt * 4 + ns) * 64 + ln) * 8 + j;
    Wsplit[base + off]        = (short)hi;   // hi: first 16 KB of image
    Wsplit[base + 8192 + off] = (short)lo;   // lo: second 16 KB
}

#define STAGE_W(sW, Wfrag, tid)                                    \
    {                                                              \
        const float4* gsrc = (const float4*)(Wfrag);               \
        float4* ldst = (float4*)(sW);                              \
        _Pragma("unroll")                                          \
        for (int i = 0; i < 8; ++i)                                \
            ldst[i * TPB + (tid)] = gsrc[i * TPB + (tid)];         \
    }

// ---------------------------------------------------------------------------
// fp32-input MFMA GEMM body (3-term Markidis split), bf16 output. (layer 1)
// A: m=lane&15, k=(lane>>4)*8+j ; B mirrored ; D: col=lane&15, row=(lane>>4)*4+reg
// ---------------------------------------------------------------------------
static __device__ __forceinline__ void gemm_body_f32(
        const float* __restrict__ X, const short* __restrict__ Wfrag,
        unsigned short* __restrict__ H, int n, int tile, int colh, int tid) {
    __shared__ __align__(16) short sW[2][4][4][64][8];   // 32 KB
    STAGE_W(sW, Wfrag, tid);
    __syncthreads();

    const int lane = tid & 63;
    const int wv   = tid >> 6;
    const int q    = lane >> 4;
    const int m    = lane & 15;
    const int row0 = tile * 64 + wv * 16;
    if (row0 >= n) return;

    int rrow = row0 + m;
    if (rrow > n - 1) rrow = n - 1;

    const float4* xr = (const float4*)(X + (size_t)rrow * CH);
    float4 xa[4][2];
    #pragma unroll
    for (int kt = 0; kt < 4; ++kt) {
        xa[kt][0] = xr[kt * 8 + q * 2 + 0];
        xa[kt][1] = xr[kt * 8 + q * 2 + 1];
    }

    floatx4 acc[4];
    #pragma unroll
    for (int ns = 0; ns < 4; ++ns) acc[ns] = (floatx4){0.f, 0.f, 0.f, 0.f};

    #pragma unroll
    for (int kt = 0; kt < 4; ++kt) {
        float xf[8] = { xa[kt][0].x, xa[kt][0].y, xa[kt][0].z, xa[kt][0].w,
                        xa[kt][1].x, xa[kt][1].y, xa[kt][1].z, xa[kt][1].w };
        short8 ah, al;
        #pragma unroll
        for (int j = 0; j < 8; ++j) {
            float v = xf[j];
            unsigned short h = f2bf(v);
            ah[j] = (short)h;
            al[j] = (short)f2bf(v - bf2f(h));
        }
        #pragma unroll
        for (int ns = 0; ns < 4; ++ns) {
            short8 bh = *(const short8*)&sW[0][kt][ns][lane][0];
            short8 bl = *(const short8*)&sW[1][kt][ns][lane][0];
            acc[ns] = __builtin_amdgcn_mfma_f32_16x16x32_bf16(ah, bh, acc[ns], 0, 0, 0);
            acc[ns] = __builtin_amdgcn_mfma_f32_16x16x32_bf16(al, bh, acc[ns], 0, 0, 0);
            acc[ns] = __builtin_amdgcn_mfma_f32_16x16x32_bf16(ah, bl, acc[ns], 0, 0, 0);
        }
    }

    #pragma unroll
    for (int ns = 0; ns < 4; ++ns) {
        #pragma unroll
        for (int reg = 0; reg < 4; ++reg) {
            int r = row0 + q * 4 + reg;
            if (r < n)
                H[(size_t)r * CH + colh * 64 + ns * 16 + m] = f2bf(acc[ns][reg]);
        }
    }
}

// fused: blocks [0, nbE): per-edge replicated rank atomic (long pole, first);
// blocks [nbE, ...): gemm1 (fp32 x).
__global__ __launch_bounds__(TPB, 4)
void k_gemm_rank(const float* __restrict__ X, const short* __restrict__ Wsplit,
                 unsigned short* __restrict__ H, int n,
                 const int* __restrict__ dst, int* __restrict__ counts_rep,
                 int* __restrict__ rank, int E, int nbE, int Np) {
    int bx = blockIdx.x;
    if (bx < nbE) {
        int e = bx * TPB + threadIdx.x;
        if (e < E) {
            int d = dst[e];
            if ((unsigned)d < (unsigned)n) {
                int rep = e & (NREP - 1);
                rank[e] = atomicAdd(&counts_rep[rep * Np + d], 1);
            }
        }
    } else {
        bx -= nbE;
        int colh = bx & 1;
        gemm_body_f32(X, Wsplit + (size_t)colh * WIMG, H, n, bx >> 1, colh,
                      threadIdx.x);
    }
}

// ---------------------------------------------------------------------------
// scan1: sum 8 replica counts -> counts_tot, replica-exclusive offsets
// (repoff8, 8 ints/node), block-local exclusive scan -> row_start, and the
// last-finishing block top-scans partials into pp_s (exclusive).
// Absolute bucket base = row_start[i] + pp_s[i >> 10].
// ---------------------------------------------------------------------------
__global__ __launch_bounds__(SCANB)
void k_scan1(const int* __restrict__ counts_rep, int Np,
             int* __restrict__ counts_tot, int* __restrict__ repoff8,
             int* __restrict__ row_start, int* __restrict__ partials,
             int* __restrict__ pp_s, int* __restrict__ done, int nb, int n) {
    __shared__ int s[SCANB];
    __shared__ int slast;
    int gid = blockIdx.x * SCANB + threadIdx.x;
    int c[NREP];
    int v = 0;
    #pragma unroll
    for (int r = 0; r < NREP; ++r) {
        c[r] = (gid < n) ? counts_rep[r * Np + gid] : 0;
        v += c[r];
    }
    s[threadIdx.x] = v;
    __syncthreads();
    for (int off = 1; off < SCANB; off <<= 1) {
        int t = (threadIdx.x >= off) ? s[threadIdx.x - off] : 0;
        __syncthreads();
        s[threadIdx.x] += t;
        __syncthreads();
    }
    if (gid < n) {
        row_start[gid]  = s[threadIdx.x] - v;   // block-local exclusive
        counts_tot[gid] = v;
        int pre = 0;
        int ro[NREP];
        #pragma unroll
        for (int r = 0; r < NREP; ++r) { ro[r] = pre; pre += c[r]; }
        ((int4*)repoff8)[gid * 2 + 0] = make_int4(ro[0], ro[1], ro[2], ro[3]);
        ((int4*)repoff8)[gid * 2 + 1] = make_int4(ro[4], ro[5], ro[6], ro[7]);
    }
    if (threadIdx.x == SCANB - 1) {
        partials[blockIdx.x] = s[SCANB - 1];
        __threadfence();
        int old = atomicAdd(done, 1);
        slast = (old == nb - 1);
    }
    __syncthreads();
    if (slast && threadIdx.x < 64) {
        int pv = (threadIdx.x < nb) ? atomicAdd(&partials[threadIdx.x], 0) : 0;
        int inc = pv;
        #pragma unroll
        for (int off = 1; off < 64; off <<= 1) {
            int t = __shfl_up(inc, off, 64);
            if ((threadIdx.x & 63) >= off) inc += t;
        }
        if (threadIdx.x < nb) pp_s[threadIdx.x] = inc - pv;
    }
}

// atomic-free fill
__global__ void k_fill(const int* __restrict__ src, const int* __restrict__ dst,
                       const float* __restrict__ ew, const int* __restrict__ row_start,
                       const int* __restrict__ pp_s, const int* __restrict__ repoff8,
                       const int* __restrict__ rank, int2* __restrict__ edges,
                       int E, int n) {
    int e = blockIdx.x * blockDim.x + threadIdx.x;
    if (e >= E) return;
    int s = src[e], d = dst[e];
    if ((unsigned)s >= (unsigned)n || (unsigned)d >= (unsigned)n) return;
    int rep = e & (NREP - 1);
    int base = row_start[d] + pp_s[d >> 10] + repoff8[d * NREP + rep];
    edges[base + rank[e]] = make_int2(s, __float_as_int(ew[e]));
}

// per-node: deg = 1 + sum(raw ew over bucket); dinv = rsqrt(deg)
__global__ void k_deg(const int* __restrict__ row_start, const int* __restrict__ pp_s,
                      const int* __restrict__ counts, const int2* __restrict__ edges,
                      float* __restrict__ dinv, int n) {
    int i = blockIdx.x * blockDim.x + threadIdx.x;
    if (i >= n) return;
    int j = row_start[i] + pp_s[i >> 10], end = j + counts[i];
    float sum = 1.0f;
    for (; j < end; ++j) sum += __int_as_float(edges[j].y);
    dinv[i] = rsqrtf(sum);
}

// ---------------------------------------------------------------------------
// shared aggregate core: returns o = h[node]*di^2 + bias + di*sum(w'*h[src])
// FIXUP: w' = raw_ew*dinv[src] computed and written back; txz = (tx==0) lane.
// Executed per (half-)wave group of 32 lanes, tx in [0,32).
// ---------------------------------------------------------------------------
template<int FIXUP>
static __device__ __forceinline__ float4 agg_node(
        const ushort4* __restrict__ h4, int2* __restrict__ edges,
        const float* __restrict__ dinv, const float4 b, int node, int tx,
        const int* __restrict__ row_start, const int* __restrict__ pp_s,
        const int* __restrict__ counts) {
    float di = dinv[node];
    float4 hv = bf4_to_f4(h4[(size_t)node * CH4 + tx]);
    float4 acc = make_float4(0.f, 0.f, 0.f, 0.f);
    int j   = row_start[node] + pp_s[node >> 10];
    int end = j + counts[node];

    for (; j + 8 <= end; j += 8) {
        int2 e[8];
        #pragma unroll
        for (int i = 0; i < 8; ++i) e[i] = edges[j + i];
        ushort4 g[8];
        #pragma unroll
        for (int i = 0; i < 8; ++i) g[i] = h4[(size_t)e[i].x * CH4 + tx];
        float w[8];
        #pragma unroll
        for (int i = 0; i < 8; ++i) {
            w[i] = __int_as_float(e[i].y);
            if (FIXUP) w[i] *= dinv[e[i].x];
        }
        if (FIXUP && tx == 0) {
            #pragma unroll
            for (int i = 0; i < 8; ++i) edges[j + i].y = __float_as_int(w[i]);
        }
        #pragma unroll
        for (int i = 0; i < 8; ++i) {
            float4 gf = bf4_to_f4(g[i]);
            acc.x += gf.x * w[i]; acc.y += gf.y * w[i];
            acc.z += gf.z * w[i]; acc.w += gf.w * w[i];
        }
    }
    if (j + 4 <= end) {
        int2 e[4];
        #pragma unroll
        for (int i = 0; i < 4; ++i) e[i] = edges[j + i];
        ushort4 g[4];
        #pragma unroll
        for (int i = 0; i < 4; ++i) g[i] = h4[(size_t)e[i].x * CH4 + tx];
        float w[4];
        #pragma unroll
        for (int i = 0; i < 4; ++i) {
            w[i] = __int_as_float(e[i].y);
            if (FIXUP) w[i] *= dinv[e[i].x];
        }
        if (FIXUP && tx == 0) {
            #pragma unroll
            for (int i = 0; i < 4; ++i) edges[j + i].y = __float_as_int(w[i]);
        }
        #pragma unroll
        for (int i = 0; i < 4; ++i) {
            float4 gf = bf4_to_f4(g[i]);
            acc.x += gf.x * w[i]; acc.y += gf.y * w[i];
            acc.z += gf.z * w[i]; acc.w += gf.w * w[i];
        }
        j += 4;
    }
    for (; j < end; ++j) {
        int2 e0 = edges[j];
        float w0 = __int_as_float(e0.y);
        if (FIXUP) w0 *= dinv[e0.x];
        if (FIXUP && tx == 0) edges[j].y = __float_as_int(w0);
        float4 gf = bf4_to_f4(h4[(size_t)e0.x * CH4 + tx]);
        acc.x += gf.x * w0; acc.y += gf.y * w0;
        acc.z += gf.z * w0; acc.w += gf.w * w0;
    }

    float sc = di * di;
    return make_float4(hv.x * sc + b.x + di * acc.x,
                       hv.y * sc + b.y + di * acc.y,
                       hv.z * sc + b.z + di * acc.z,
                       hv.w * sc + b.w + di * acc.w);
}

// ---------------------------------------------------------------------------
// FUSED agg1 + gemm2: block owns 64 nodes.
// Phase 1: aggregate (FIXUP, +b1, ReLU) -> bf16 LDS tile (padded pitch 136).
// Phase 2: MFMA vs W2 staged hi-only (both col halves, 32 KB) -> Hout bf16.
// LDS total ~50 KB -> 3 blocks/CU.
// ---------------------------------------------------------------------------
__global__ __launch_bounds__(TPB, 3)
void k_agg_gemm(const unsigned short* __restrict__ h,
                const int* __restrict__ row_start, const int* __restrict__ pp_s,
                const int* __restrict__ counts, int2* __restrict__ edges,
                const float* __restrict__ dinv, const float* __restrict__ bias,
                const short* __restrict__ W2frag,   // layer-2 images (colh0, colh1)
                unsigned short* __restrict__ Hout, int n) {
    __shared__ __align__(16) short sW[2][4][4][64][8];      // hi-only, 32 KB
    __shared__ __align__(16) unsigned short sA[64][136];    // 64x128 bf16, padded
    const int tid = threadIdx.x;

    // stage hi halves (first 16 KB of each colh image)
    {
        const float4* g0 = (const float4*)(W2frag);
        const float4* g1 = (const float4*)(W2frag + WIMG);
        float4* d0 = (float4*)&sW[0][0][0][0][0];
        float4* d1 = (float4*)&sW[1][0][0][0][0];
        #pragma unroll
        for (int i = 0; i < 4; ++i) {
            d0[i * TPB + tid] = g0[i * TPB + tid];
            d1[i * TPB + tid] = g1[i * TPB + tid];
        }
    }

    const int lane = tid & 63;
    const int wv   = tid >> 6;
    const int half = lane >> 5;
    const int tx   = lane & 31;
    const ushort4* h4 = (const ushort4*)h;
    const float4 b = ((const float4*)bias)[tx];

    // phase 1: each half-wave aggregates 8 nodes sequentially
    for (int nd = 0; nd < 8; ++nd) {
        int nl   = wv * 16 + nd * 2 + half;          // 0..63
        int node = blockIdx.x * 64 + nl;
        ushort4 u = make_ushort4(0, 0, 0, 0);
        if (node < n) {
            float4 o = agg_node<1>(h4, edges, dinv, b, node, tx,
                                   row_start, pp_s, counts);
            u = make_ushort4(f2bf(fmaxf(o.x, 0.f)), f2bf(fmaxf(o.y, 0.f)),
                             f2bf(fmaxf(o.z, 0.f)), f2bf(fmaxf(o.w, 0.f)));
        }
        *(ushort4*)&sA[nl][tx * 4] = u;
    }
    __syncthreads();

    // phase 2: wave wv does rows [wv*16, wv*16+16) x 128 cols, W2 hi-only
    const int q = lane >> 4;
    const int m = lane & 15;
    short8 a[4];
    #pragma unroll
    for (int kt = 0; kt < 4; ++kt)
        a[kt] = *(const short8*)&sA[wv * 16 + m][kt * 32 + q * 8];

    floatx4 acc[8];
    #pragma unroll
    for (int s2 = 0; s2 < 8; ++s2) acc[s2] = (floatx4){0.f, 0.f, 0.f, 0.f};

    #pragma unroll
    for (int kt = 0; kt < 4; ++kt) {
        #pragma unroll
        for (int s2 = 0; s2 < 8; ++s2) {
            short8 bh = *(const short8*)&sW[s2 >> 2][kt][s2 & 3][lane][0];
            acc[s2] = __builtin_amdgcn_mfma_f32_16x16x32_bf16(a[kt], bh, acc[s2], 0, 0, 0);
        }
    }

    const int row0 = blockIdx.x * 64 + wv * 16;
    #pragma unroll
    for (int s2 = 0; s2 < 8; ++s2) {
        int col = (s2 >> 2) * 64 + (s2 & 3) * 16 + m;
        #pragma unroll
        for (int reg = 0; reg < 4; ++reg) {
            int r = row0 + q * 4 + reg;
            if (r < n)
                Hout[(size_t)r * CH + col] = f2bf(acc[s2][reg]);
        }
    }
}

// ---------------------------------------------------------------------------
// agg2: out = relu( h2*di^2 + b2 + di*sum(w'*h2[src]) ), fp32 out
// ---------------------------------------------------------------------------
__global__ __launch_bounds__(TPB)
void k_aggregate2(const unsigned short* __restrict__ h,
                  const int* __restrict__ row_start, const int* __restrict__ pp_s,
                  const int* __restrict__ counts, int2* __restrict__ edges,
                  const float* __restrict__ dinv, const float* __restrict__ bias,
                  float* __restrict__ out, int n) {
    int t = blockIdx.x * blockDim.x + threadIdx.x;
    int node = t >> 5;
    if (node >= n) return;
    int tx = t & 31;
    const float4 b = ((const float4*)bias)[tx];
    float4 o = agg_node<0>((const ushort4*)h, edges, dinv, b, node, tx,
                           row_start, pp_s, counts);
    o.x = fmaxf(o.x, 0.f); o.y = fmaxf(o.y, 0.f);
    o.z = fmaxf(o.z, 0.f); o.w = fmaxf(o.w, 0.f);
    ((float4*)out)[(size_t)node * CH4 + tx] = o;
}

// ---------------------------------------------------------------------------
extern "C" void kernel_launch(void* const* d_in, const int* in_sizes, int n_in,
                              void* d_out, int out_size, void* d_ws, size_t ws_size,
                              hipStream_t stream) {
    const float* x  = (const float*)d_in[0];   // [N,128]
    const int*   ei = (const int*)d_in[1];     // [2,E]
    const float* ew = (const float*)d_in[2];   // [E]
    const float* W1 = (const float*)d_in[3];
    const float* b1 = (const float*)d_in[4];
    const float* W2 = (const float*)d_in[5];
    const float* b2 = (const float*)d_in[6];
    float* out = (float*)d_out;                // [N,128]

    const int N = in_sizes[0] / CH;
    const int E = in_sizes[2];
    const int* src = ei;
    const int* dst = ei + E;

    // workspace layout (16B-aligned)
    size_t Np = ((size_t)N + 255) & ~(size_t)255;
    size_t Ep = ((size_t)E + 63) & ~(size_t)63;
    float* ws          = (float*)d_ws;
    float* dinv        = ws;                                // Np floats
    unsigned short* h  = (unsigned short*)(dinv + Np);      // N*CH bf16 (gemm1 out)
    unsigned short* h2 = h + (size_t)N * CH;                // N*CH bf16 (gemm2 out)
    // ---- contiguous zero region ----
    int*   counts_rep  = (int*)(h2 + (size_t)N * CH);       // NREP*Np ints
    int*   done        = counts_rep + NREP * Np;            // 64 ints (1 used)
    size_t zero_bytes  = (size_t)NREP * Np * 4 + 256;
    // ---- rest ----
    int*  counts_tot   = done + 64;                         // Np ints
    int*  row_start    = counts_tot + Np;                   // Np ints
    int*  repoff8      = row_start + Np;                    // NREP*Np ints
    int*  rank         = repoff8 + NREP * Np;               // Ep ints
    int*  partials     = rank + Ep;                         // 64 ints
    int*  pp_s         = partials + 64;                     // 64 ints
    int2* edges        = (int2*)(pp_s + 64);                // E int2
    short* Wsplit      = (short*)(edges + E);               // 4*WIMG shorts

    const int nbN    = (N + TPB - 1) / TPB;
    const int nbE    = (E + TPB - 1) / TPB;
    const int nbAgg  = (int)(((size_t)N * 32 + TPB - 1) / TPB);
    const int nbScan = (N + SCANB - 1) / SCANB;     // 49 <= 64
    const int nbT64  = (N + 63) / 64;               // 782
    const int nbGemm2 = 2 * nbT64;
    const int nbPrep  = (2 * CH * CH + TPB - 1) / TPB;

    // ---- prep: zero counters+done, split W ----
    hipMemsetAsync(counts_rep, 0, zero_bytes, stream);
    k_prep     <<<nbPrep, TPB, 0, stream>>>(W1, W2, Wsplit);

    // ---- fused: replicated rank pass | gemm1 (h = x@W1, bf16) ----
    k_gemm_rank<<<nbE + nbGemm2, TPB, 0, stream>>>(x, Wsplit, h, N, dst,
                                                   counts_rep, rank, E, nbE, (int)Np);
    // ---- CSR finalize ----
    k_scan1    <<<nbScan, SCANB, 0, stream>>>(counts_rep, (int)Np, counts_tot,
                                              repoff8, row_start, partials,
                                              pp_s, done, nbScan, N);
    k_fill     <<<nbE, TPB, 0, stream>>>(src, dst, ew, row_start, pp_s, repoff8,
                                         rank, edges, E, N);
    k_deg      <<<nbN, TPB, 0, stream>>>(row_start, pp_s, counts_tot, edges,
                                         dinv, N);

    // ---- fused agg1 (FIXUP, +b1, ReLU) -> LDS -> gemm2 (W2 hi) -> h2 ----
    k_agg_gemm <<<nbT64, TPB, 0, stream>>>(h, row_start, pp_s, counts_tot,
                                           edges, dinv, b1,
                                           Wsplit + 2 * (size_t)WIMG, h2, N);
    // ---- agg2 -> out (fp32) ----
    k_aggregate2<<<nbAgg, TPB, 0, stream>>>(h2, row_start, pp_s, counts_tot,
                                            edges, dinv, b2, out, N);
}

// Round 12
// 228.454 us; speedup vs baseline: 1.1002x; 1.1002x over previous
//
#include <hip/hip_runtime.h>
#include <math.h>

// GCN 2-layer forward on MI355X — round 12: revert r11's agg+gemm fusion
// (regressed: serialized gather in 782 blocks) back to the r9 structure;
// keep pp_s fused top-scan (no scan3), NREP=8 rank counters, and W2 hi-only
// in gemm2 (r11 showed absmax unaffected).
#define CH   128
#define CH4  32
#define TPB  256
#define SCANB 1024
#define WIMG 16384       // shorts per (layer,colh) fragment image (32 KB)
#define NREP 8

typedef __attribute__((ext_vector_type(8))) short short8;   // 8 bf16 (4 VGPRs)
typedef __attribute__((ext_vector_type(4))) float floatx4;  // MFMA acc

static __device__ __forceinline__ unsigned short f2bf(float f) {
    unsigned u = __float_as_uint(f);
    return (unsigned short)((u + 0x7fffu + ((u >> 16) & 1u)) >> 16);
}
static __device__ __forceinline__ float bf2f(unsigned short s) {
    return __uint_as_float(((unsigned)s) << 16);
}
static __device__ __forceinline__ float4 bf4_to_f4(ushort4 u) {
    return make_float4(bf2f(u.x), bf2f(u.y), bf2f(u.z), bf2f(u.w));
}

// ---------------------------------------------------------------------------
// k_prep: split W1,W2 into bf16 hi/lo B-fragment images (32 KB per colh).
// ---------------------------------------------------------------------------
__global__ void k_prep(const float* __restrict__ W1, const float* __restrict__ W2,
                       short* __restrict__ Wsplit) {
    int i = blockIdx.x * blockDim.x + threadIdx.x;   // over 2*128*128
    if (i >= 2 * CH * CH) return;
    int layer = i >> 14;
    int idx   = i & 16383;
    int k = idx >> 7, c = idx & 127;
    float w = (layer ? W2 : W1)[k * CH + c];
    unsigned short hi = f2bf(w);
    unsigned short lo = f2bf(w - bf2f(hi));
    int colh = c >> 6, nn = c & 63;
    int kt = k >> 5, q = (k & 31) >> 3, j = k & 7;
    int ns = nn >> 4, ln = q * 16 + (nn & 15);
    size_t base = (size_t)(layer * 2 + colh) * WIMG;
    size_t off  = ((size_t)(kt * 4 + ns) * 64 + ln) * 8 + j;
    Wsplit[base + off]        = (short)hi;   // hi: first 16 KB of image
    Wsplit[base + 8192 + off] = (short)lo;   // lo: second 16 KB
}

// ---------------------------------------------------------------------------
// fp32-input MFMA GEMM body (3-term Markidis split), bf16 output. (layer 1)
// A: m=lane&15, k=(lane>>4)*8+j ; B mirrored ; D: col=lane&15, row=(lane>>4)*4+reg
// ---------------------------------------------------------------------------
static __device__ __forceinline__ void gemm_body_f32(
        const float* __restrict__ X, const short* __restrict__ Wfrag,
        unsigned short* __restrict__ H, int n, int tile, int colh, int tid) {
    __shared__ __align__(16) short sW[2][4][4][64][8];   // 32 KB (hi+lo)
    {
        const float4* gsrc = (const float4*)Wfrag;
        float4* ldst = (float4*)sW;
        #pragma unroll
        for (int i = 0; i < 8; ++i)
            ldst[i * TPB + tid] = gsrc[i * TPB + tid];
    }
    __syncthreads();

    const int lane = tid & 63;
    const int wv   = tid >> 6;
    const int q    = lane >> 4;
    const int m    = lane & 15;
    const int row0 = tile * 64 + wv * 16;
    if (row0 >= n) return;

    int rrow = row0 + m;
    if (rrow > n - 1) rrow = n - 1;

    const float4* xr = (const float4*)(X + (size_t)rrow * CH);
    float4 xa[4][2];
    #pragma unroll
    for (int kt = 0; kt < 4; ++kt) {
        xa[kt][0] = xr[kt * 8 + q * 2 + 0];
        xa[kt][1] = xr[kt * 8 + q * 2 + 1];
    }

    floatx4 acc[4];
    #pragma unroll
    for (int ns = 0; ns < 4; ++ns) acc[ns] = (floatx4){0.f, 0.f, 0.f, 0.f};

    #pragma unroll
    for (int kt = 0; kt < 4; ++kt) {
        float xf[8] = { xa[kt][0].x, xa[kt][0].y, xa[kt][0].z, xa[kt][0].w,
                        xa[kt][1].x, xa[kt][1].y, xa[kt][1].z, xa[kt][1].w };
        short8 ah, al;
        #pragma unroll
        for (int j = 0; j < 8; ++j) {
            float v = xf[j];
            unsigned short h = f2bf(v);
            ah[j] = (short)h;
            al[j] = (short)f2bf(v - bf2f(h));
        }
        #pragma unroll
        for (int ns = 0; ns < 4; ++ns) {
            short8 bh = *(const short8*)&sW[0][kt][ns][lane][0];
            short8 bl = *(const short8*)&sW[1][kt][ns][lane][0];
            acc[ns] = __builtin_amdgcn_mfma_f32_16x16x32_bf16(ah, bh, acc[ns], 0, 0, 0);
            acc[ns] = __builtin_amdgcn_mfma_f32_16x16x32_bf16(al, bh, acc[ns], 0, 0, 0);
            acc[ns] = __builtin_amdgcn_mfma_f32_16x16x32_bf16(ah, bl, acc[ns], 0, 0, 0);
        }
    }

    #pragma unroll
    for (int ns = 0; ns < 4; ++ns) {
        #pragma unroll
        for (int reg = 0; reg < 4; ++reg) {
            int r = row0 + q * 4 + reg;
            if (r < n)
                H[(size_t)r * CH + colh * 64 + ns * 16 + m] = f2bf(acc[ns][reg]);
        }
    }
}

// fused: blocks [0, nbE): per-edge replicated rank atomic (long pole, first);
// blocks [nbE, ...): gemm1 (fp32 x).
__global__ __launch_bounds__(TPB, 4)
void k_gemm_rank(const float* __restrict__ X, const short* __restrict__ Wsplit,
                 unsigned short* __restrict__ H, int n,
                 const int* __restrict__ dst, int* __restrict__ counts_rep,
                 int* __restrict__ rank, int E, int nbE, int Np) {
    int bx = blockIdx.x;
    if (bx < nbE) {
        int e = bx * TPB + threadIdx.x;
        if (e < E) {
            int d = dst[e];
            if ((unsigned)d < (unsigned)n) {
                int rep = e & (NREP - 1);
                rank[e] = atomicAdd(&counts_rep[rep * Np + d], 1);
            }
        }
    } else {
        bx -= nbE;
        int colh = bx & 1;
        gemm_body_f32(X, Wsplit + (size_t)colh * WIMG, H, n, bx >> 1, colh,
                      threadIdx.x);
    }
}

// bf16-input GEMM, W2 hi-only (1 MFMA/frag, 16 KB LDS). (layer 2)
__global__ __launch_bounds__(TPB, 4)
void k_gemm_bf(const unsigned short* __restrict__ X, const short* __restrict__ Wsplit,
               unsigned short* __restrict__ H, int n) {
    __shared__ __align__(16) short sW[4][4][64][8];      // hi-only, 16 KB
    const int tid  = threadIdx.x;
    const int colh = (int)blockIdx.x & 1;
    const int tile = (int)blockIdx.x >> 1;
    {
        const float4* gsrc = (const float4*)(Wsplit + (size_t)colh * WIMG); // hi half
        float4* ldst = (float4*)sW;
        #pragma unroll
        for (int i = 0; i < 4; ++i)
            ldst[i * TPB + tid] = gsrc[i * TPB + tid];
    }
    __syncthreads();

    const int lane = tid & 63;
    const int wv   = tid >> 6;
    const int q    = lane >> 4;
    const int m    = lane & 15;
    const int row0 = tile * 64 + wv * 16;
    if (row0 >= n) return;

    int rrow = row0 + m;
    if (rrow > n - 1) rrow = n - 1;

    const short8* xr8 = (const short8*)(X + (size_t)rrow * CH);
    short8 a[4];
    #pragma unroll
    for (int kt = 0; kt < 4; ++kt) a[kt] = xr8[kt * 4 + q];

    floatx4 acc[4];
    #pragma unroll
    for (int ns = 0; ns < 4; ++ns) acc[ns] = (floatx4){0.f, 0.f, 0.f, 0.f};

    #pragma unroll
    for (int kt = 0; kt < 4; ++kt) {
        #pragma unroll
        for (int ns = 0; ns < 4; ++ns) {
            short8 bh = *(const short8*)&sW[kt][ns][lane][0];
            acc[ns] = __builtin_amdgcn_mfma_f32_16x16x32_bf16(a[kt], bh, acc[ns], 0, 0, 0);
        }
    }

    #pragma unroll
    for (int ns = 0; ns < 4; ++ns) {
        #pragma unroll
        for (int reg = 0; reg < 4; ++reg) {
            int r = row0 + q * 4 + reg;
            if (r < n)
                H[(size_t)r * CH + colh * 64 + ns * 16 + m] = f2bf(acc[ns][reg]);
        }
    }
}

// ---------------------------------------------------------------------------
// scan1: sum 8 replica counts -> counts_tot, replica-exclusive offsets,
// block-local exclusive scan -> row_start; last-finishing block top-scans
// partials into pp_s. Absolute bucket base = row_start[i] + pp_s[i >> 10].
// ---------------------------------------------------------------------------
__global__ __launch_bounds__(SCANB)
void k_scan1(const int* __restrict__ counts_rep, int Np,
             int* __restrict__ counts_tot, int* __restrict__ repoff8,
             int* __restrict__ row_start, int* __restrict__ partials,
             int* __restrict__ pp_s, int* __restrict__ done, int nb, int n) {
    __shared__ int s[SCANB];
    __shared__ int slast;
    int gid = blockIdx.x * SCANB + threadIdx.x;
    int c[NREP];
    int v = 0;
    #pragma unroll
    for (int r = 0; r < NREP; ++r) {
        c[r] = (gid < n) ? counts_rep[r * Np + gid] : 0;
        v += c[r];
    }
    s[threadIdx.x] = v;
    __syncthreads();
    for (int off = 1; off < SCANB; off <<= 1) {
        int t = (threadIdx.x >= off) ? s[threadIdx.x - off] : 0;
        __syncthreads();
        s[threadIdx.x] += t;
        __syncthreads();
    }
    if (gid < n) {
        row_start[gid]  = s[threadIdx.x] - v;   // block-local exclusive
        counts_tot[gid] = v;
        int pre = 0;
        int ro[NREP];
        #pragma unroll
        for (int r = 0; r < NREP; ++r) { ro[r] = pre; pre += c[r]; }
        ((int4*)repoff8)[gid * 2 + 0] = make_int4(ro[0], ro[1], ro[2], ro[3]);
        ((int4*)repoff8)[gid * 2 + 1] = make_int4(ro[4], ro[5], ro[6], ro[7]);
    }
    if (threadIdx.x == SCANB - 1) {
        partials[blockIdx.x] = s[SCANB - 1];
        __threadfence();
        int old = atomicAdd(done, 1);
        slast = (old == nb - 1);
    }
    __syncthreads();
    if (slast && threadIdx.x < 64) {
        int pv = (threadIdx.x < nb) ? atomicAdd(&partials[threadIdx.x], 0) : 0;
        int inc = pv;
        #pragma unroll
        for (int off = 1; off < 64; off <<= 1) {
            int t = __shfl_up(inc, off, 64);
            if ((threadIdx.x & 63) >= off) inc += t;
        }
        if (threadIdx.x < nb) pp_s[threadIdx.x] = inc - pv;
    }
}

// atomic-free fill
__global__ void k_fill(const int* __restrict__ src, const int* __restrict__ dst,
                       const float* __restrict__ ew, const int* __restrict__ row_start,
                       const int* __restrict__ pp_s, const int* __restrict__ repoff8,
                       const int* __restrict__ rank, int2* __restrict__ edges,
                       int E, int n) {
    int e = blockIdx.x * blockDim.x + threadIdx.x;
    if (e >= E) return;
    int s = src[e], d = dst[e];
    if ((unsigned)s >= (unsigned)n || (unsigned)d >= (unsigned)n) return;
    int rep = e & (NREP - 1);
    int base = row_start[d] + pp_s[d >> 10] + repoff8[d * NREP + rep];
    edges[base + rank[e]] = make_int2(s, __float_as_int(ew[e]));
}

// per-node: deg = 1 + sum(raw ew over bucket); dinv = rsqrt(deg)
__global__ void k_deg(const int* __restrict__ row_start, const int* __restrict__ pp_s,
                      const int* __restrict__ counts, const int2* __restrict__ edges,
                      float* __restrict__ dinv, int n) {
    int i = blockIdx.x * blockDim.x + threadIdx.x;
    if (i >= n) return;
    int j = row_start[i] + pp_s[i >> 10], end = j + counts[i];
    float sum = 1.0f;
    for (; j < end; ++j) sum += __int_as_float(edges[j].y);
    dinv[i] = rsqrtf(sum);
}

// ---------------------------------------------------------------------------
// aggregate core: o = h[node]*di^2 + bias + di*sum(w'*h[src])
// FIXUP: w' = raw_ew*dinv[src], written back by lane tx==0.
// ---------------------------------------------------------------------------
template<int FIXUP>
static __device__ __forceinline__ float4 agg_node(
        const ushort4* __restrict__ h4, int2* __restrict__ edges,
        const float* __restrict__ dinv, const float4 b, int node, int tx,
        const int* __restrict__ row_start, const int* __restrict__ pp_s,
        const int* __restrict__ counts) {
    float di = dinv[node];
    float4 hv = bf4_to_f4(h4[(size_t)node * CH4 + tx]);
    float4 acc = make_float4(0.f, 0.f, 0.f, 0.f);
    int j   = row_start[node] + pp_s[node >> 10];
    int end = j + counts[node];

    for (; j + 8 <= end; j += 8) {
        int2 e[8];
        #pragma unroll
        for (int i = 0; i < 8; ++i) e[i] = edges[j + i];
        ushort4 g[8];
        #pragma unroll
        for (int i = 0; i < 8; ++i) g[i] = h4[(size_t)e[i].x * CH4 + tx];
        float w[8];
        #pragma unroll
        for (int i = 0; i < 8; ++i) {
            w[i] = __int_as_float(e[i].y);
            if (FIXUP) w[i] *= dinv[e[i].x];
        }
        if (FIXUP && tx == 0) {
            #pragma unroll
            for (int i = 0; i < 8; ++i) edges[j + i].y = __float_as_int(w[i]);
        }
        #pragma unroll
        for (int i = 0; i < 8; ++i) {
            float4 gf = bf4_to_f4(g[i]);
            acc.x += gf.x * w[i]; acc.y += gf.y * w[i];
            acc.z += gf.z * w[i]; acc.w += gf.w * w[i];
        }
    }
    if (j + 4 <= end) {
        int2 e[4];
        #pragma unroll
        for (int i = 0; i < 4; ++i) e[i] = edges[j + i];
        ushort4 g[4];
        #pragma unroll
        for (int i = 0; i < 4; ++i) g[i] = h4[(size_t)e[i].x * CH4 + tx];
        float w[4];
        #pragma unroll
        for (int i = 0; i < 4; ++i) {
            w[i] = __int_as_float(e[i].y);
            if (FIXUP) w[i] *= dinv[e[i].x];
        }
        if (FIXUP && tx == 0) {
            #pragma unroll
            for (int i = 0; i < 4; ++i) edges[j + i].y = __float_as_int(w[i]);
        }
        #pragma unroll
        for (int i = 0; i < 4; ++i) {
            float4 gf = bf4_to_f4(g[i]);
            acc.x += gf.x * w[i]; acc.y += gf.y * w[i];
            acc.z += gf.z * w[i]; acc.w += gf.w * w[i];
        }
        j += 4;
    }
    for (; j < end; ++j) {
        int2 e0 = edges[j];
        float w0 = __int_as_float(e0.y);
        if (FIXUP) w0 *= dinv[e0.x];
        if (FIXUP && tx == 0) edges[j].y = __float_as_int(w0);
        float4 gf = bf4_to_f4(h4[(size_t)e0.x * CH4 + tx]);
        acc.x += gf.x * w0; acc.y += gf.y * w0;
        acc.z += gf.z * w0; acc.w += gf.w * w0;
    }

    float sc = di * di;
    return make_float4(hv.x * sc + b.x + di * acc.x,
                       hv.y * sc + b.y + di * acc.y,
                       hv.z * sc + b.z + di * acc.z,
                       hv.w * sc + b.w + di * acc.w);
}

// agg1: o1 = relu(agg(h)) in bf16; computes+stores w' (FIXUP)
__global__ __launch_bounds__(TPB)
void k_aggregate1(const unsigned short* __restrict__ h,
                  const int* __restrict__ row_start, const int* __restrict__ pp_s,
                  const int* __restrict__ counts, int2* __restrict__ edges,
                  const float* __restrict__ dinv, const float* __restrict__ bias,
                  unsigned short* __restrict__ out, int n) {
    int t = blockIdx.x * blockDim.x + threadIdx.x;
    int node = t >> 5;
    if (node >= n) return;
    int tx = t & 31;
    const float4 b = ((const float4*)bias)[tx];
    float4 o = agg_node<1>((const ushort4*)h, edges, dinv, b, node, tx,
                           row_start, pp_s, counts);
    ushort4 u = make_ushort4(f2bf(fmaxf(o.x, 0.f)), f2bf(fmaxf(o.y, 0.f)),
                             f2bf(fmaxf(o.z, 0.f)), f2bf(fmaxf(o.w, 0.f)));
    ((ushort4*)out)[(size_t)node * CH4 + tx] = u;
}

// agg2: out = relu(agg(h2)) in fp32
__global__ __launch_bounds__(TPB)
void k_aggregate2(const unsigned short* __restrict__ h,
                  const int* __restrict__ row_start, const int* __restrict__ pp_s,
                  const int* __restrict__ counts, int2* __restrict__ edges,
                  const float* __restrict__ dinv, const float* __restrict__ bias,
                  float* __restrict__ out, int n) {
    int t = blockIdx.x * blockDim.x + threadIdx.x;
    int node = t >> 5;
    if (node >= n) return;
    int tx = t & 31;
    const float4 b = ((const float4*)bias)[tx];
    float4 o = agg_node<0>((const ushort4*)h, edges, dinv, b, node, tx,
                           row_start, pp_s, counts);
    o.x = fmaxf(o.x, 0.f); o.y = fmaxf(o.y, 0.f);
    o.z = fmaxf(o.z, 0.f); o.w = fmaxf(o.w, 0.f);
    ((float4*)out)[(size_t)node * CH4 + tx] = o;
}

// ---------------------------------------------------------------------------
extern "C" void kernel_launch(void* const* d_in, const int* in_sizes, int n_in,
                              void* d_out, int out_size, void* d_ws, size_t ws_size,
                              hipStream_t stream) {
    const float* x  = (const float*)d_in[0];   // [N,128]
    const int*   ei = (const int*)d_in[1];     // [2,E]
    const float* ew = (const float*)d_in[2];   // [E]
    const float* W1 = (const float*)d_in[3];
    const float* b1 = (const float*)d_in[4];
    const float* W2 = (const float*)d_in[5];
    const float* b2 = (const float*)d_in[6];
    float* out = (float*)d_out;                // [N,128]

    const int N = in_sizes[0] / CH;
    const int E = in_sizes[2];
    const int* src = ei;
    const int* dst = ei + E;

    // workspace layout (16B-aligned)
    size_t Np = ((size_t)N + 255) & ~(size_t)255;
    size_t Ep = ((size_t)E + 63) & ~(size_t)63;
    float* ws          = (float*)d_ws;
    float* dinv        = ws;                                // Np floats
    unsigned short* h  = (unsigned short*)(dinv + Np);      // N*CH bf16 (gemm1 out)
    unsigned short* o1 = h + (size_t)N * CH;                // N*CH bf16 (agg1 out)
    unsigned short* h2 = o1 + (size_t)N * CH;               // N*CH bf16 (gemm2 out)
    // ---- contiguous zero region ----
    int*   counts_rep  = (int*)(h2 + (size_t)N * CH);       // NREP*Np ints
    int*   done        = counts_rep + NREP * Np;            // 64 ints (1 used)
    size_t zero_bytes  = (size_t)NREP * Np * 4 + 256;
    // ---- rest ----
    int*  counts_tot   = done + 64;                         // Np ints
    int*  row_start    = counts_tot + Np;                   // Np ints
    int*  repoff8      = row_start + Np;                    // NREP*Np ints
    int*  rank         = repoff8 + NREP * Np;               // Ep ints
    int*  partials     = rank + Ep;                         // 64 ints
    int*  pp_s         = partials + 64;                     // 64 ints
    int2* edges        = (int2*)(pp_s + 64);                // E int2
    short* Wsplit      = (short*)(edges + E);               // 4*WIMG shorts

    const int nbN    = (N + TPB - 1) / TPB;
    const int nbE    = (E + TPB - 1) / TPB;
    const int nbAgg  = (int)(((size_t)N * 32 + TPB - 1) / TPB);
    const int nbScan = (N + SCANB - 1) / SCANB;     // 49 <= 64
    const int nbGemm2 = 2 * ((N + 63) / 64);
    const int nbPrep  = (2 * CH * CH + TPB - 1) / TPB;

    // ---- prep: zero counters+done, split W ----
    hipMemsetAsync(counts_rep, 0, zero_bytes, stream);
    k_prep     <<<nbPrep, TPB, 0, stream>>>(W1, W2, Wsplit);

    // ---- fused: replicated rank pass | gemm1 (h = x@W1, bf16) ----
    k_gemm_rank<<<nbE + nbGemm2, TPB, 0, stream>>>(x, Wsplit, h, N, dst,
                                                   counts_rep, rank, E, nbE, (int)Np);
    // ---- CSR finalize ----
    k_scan1    <<<nbScan, SCANB, 0, stream>>>(counts_rep, (int)Np, counts_tot,
                                              repoff8, row_start, partials,
                                              pp_s, done, nbScan, N);
    k_fill     <<<nbE, TPB, 0, stream>>>(src, dst, ew, row_start, pp_s, repoff8,
                                         rank, edges, E, N);
    k_deg      <<<nbN, TPB, 0, stream>>>(row_start, pp_s, counts_tot, edges,
                                         dinv, N);

    // ---- layer 1 aggregate -> o1 (bf16, ReLU); stores w' ----
    k_aggregate1<<<nbAgg, TPB, 0, stream>>>(h, row_start, pp_s, counts_tot,
                                            edges, dinv, b1, o1, N);
    // ---- layer 2 ----
    k_gemm_bf   <<<nbGemm2, TPB, 0, stream>>>(o1, Wsplit + 2 * (size_t)WIMG, h2, N);
    k_aggregate2<<<nbAgg, TPB, 0, stream>>>(h2, row_start, pp_s, counts_tot,
                                            edges, dinv, b2, out, N);
}

// Round 13
// 215.693 us; speedup vs baseline: 1.1653x; 1.0592x over previous
//
#include <hip/hip_runtime.h>
#include <math.h>

// GCN 2-layer forward on MI355X — round 13:
//  * aggregates: 16 lanes/node x 8 ch/lane (short8 16B gathers) -> 2x bytes
//    in flight per wave (latency-bound fix)
//  * rank pass: grid-stride x4 -> 4 outstanding atomics per thread
//  * otherwise r12 structure (best verified)
#define CH   128
#define CH4  32
#define TPB  256
#define SCANB 1024
#define WIMG 16384       // shorts per (layer,colh) fragment image (32 KB)
#define NREP 8

typedef __attribute__((ext_vector_type(8))) short short8;   // 8 bf16 (4 VGPRs)
typedef __attribute__((ext_vector_type(4))) float floatx4;  // MFMA acc
typedef __attribute__((ext_vector_type(8))) float float8;

static __device__ __forceinline__ unsigned short f2bf(float f) {
    unsigned u = __float_as_uint(f);
    return (unsigned short)((u + 0x7fffu + ((u >> 16) & 1u)) >> 16);
}
static __device__ __forceinline__ float bf2f(unsigned short s) {
    return __uint_as_float(((unsigned)s) << 16);
}
static __device__ __forceinline__ float8 bf8_to_f8(short8 u) {
    float8 f;
    #pragma unroll
    for (int i = 0; i < 8; ++i) f[i] = bf2f((unsigned short)u[i]);
    return f;
}

// ---------------------------------------------------------------------------
// k_prep: split W1,W2 into bf16 hi/lo B-fragment images (32 KB per colh).
// ---------------------------------------------------------------------------
__global__ void k_prep(const float* __restrict__ W1, const float* __restrict__ W2,
                       short* __restrict__ Wsplit) {
    int i = blockIdx.x * blockDim.x + threadIdx.x;   // over 2*128*128
    if (i >= 2 * CH * CH) return;
    int layer = i >> 14;
    int idx   = i & 16383;
    int k = idx >> 7, c = idx & 127;
    float w = (layer ? W2 : W1)[k * CH + c];
    unsigned short hi = f2bf(w);
    unsigned short lo = f2bf(w - bf2f(hi));
    int colh = c >> 6, nn = c & 63;
    int kt = k >> 5, q = (k & 31) >> 3, j = k & 7;
    int ns = nn >> 4, ln = q * 16 + (nn & 15);
    size_t base = (size_t)(layer * 2 + colh) * WIMG;
    size_t off  = ((size_t)(kt * 4 + ns) * 64 + ln) * 8 + j;
    Wsplit[base + off]        = (short)hi;   // hi: first 16 KB of image
    Wsplit[base + 8192 + off] = (short)lo;   // lo: second 16 KB
}

// ---------------------------------------------------------------------------
// fp32-input MFMA GEMM body (3-term Markidis split), bf16 output. (layer 1)
// A: m=lane&15, k=(lane>>4)*8+j ; B mirrored ; D: col=lane&15, row=(lane>>4)*4+reg
// ---------------------------------------------------------------------------
static __device__ __forceinline__ void gemm_body_f32(
        const float* __restrict__ X, const short* __restrict__ Wfrag,
        unsigned short* __restrict__ H, int n, int tile, int colh, int tid) {
    __shared__ __align__(16) short sW[2][4][4][64][8];   // 32 KB (hi+lo)
    {
        const float4* gsrc = (const float4*)Wfrag;
        float4* ldst = (float4*)sW;
        #pragma unroll
        for (int i = 0; i < 8; ++i)
            ldst[i * TPB + tid] = gsrc[i * TPB + tid];
    }
    __syncthreads();

    const int lane = tid & 63;
    const int wv   = tid >> 6;
    const int q    = lane >> 4;
    const int m    = lane & 15;
    const int row0 = tile * 64 + wv * 16;
    if (row0 >= n) return;

    int rrow = row0 + m;
    if (rrow > n - 1) rrow = n - 1;

    const float4* xr = (const float4*)(X + (size_t)rrow * CH);
    float4 xa[4][2];
    #pragma unroll
    for (int kt = 0; kt < 4; ++kt) {
        xa[kt][0] = xr[kt * 8 + q * 2 + 0];
        xa[kt][1] = xr[kt * 8 + q * 2 + 1];
    }

    floatx4 acc[4];
    #pragma unroll
    for (int ns = 0; ns < 4; ++ns) acc[ns] = (floatx4){0.f, 0.f, 0.f, 0.f};

    #pragma unroll
    for (int kt = 0; kt < 4; ++kt) {
        float xf[8] = { xa[kt][0].x, xa[kt][0].y, xa[kt][0].z, xa[kt][0].w,
                        xa[kt][1].x, xa[kt][1].y, xa[kt][1].z, xa[kt][1].w };
        short8 ah, al;
        #pragma unroll
        for (int j = 0; j < 8; ++j) {
            float v = xf[j];
            unsigned short h = f2bf(v);
            ah[j] = (short)h;
            al[j] = (short)f2bf(v - bf2f(h));
        }
        #pragma unroll
        for (int ns = 0; ns < 4; ++ns) {
            short8 bh = *(const short8*)&sW[0][kt][ns][lane][0];
            short8 bl = *(const short8*)&sW[1][kt][ns][lane][0];
            acc[ns] = __builtin_amdgcn_mfma_f32_16x16x32_bf16(ah, bh, acc[ns], 0, 0, 0);
            acc[ns] = __builtin_amdgcn_mfma_f32_16x16x32_bf16(al, bh, acc[ns], 0, 0, 0);
            acc[ns] = __builtin_amdgcn_mfma_f32_16x16x32_bf16(ah, bl, acc[ns], 0, 0, 0);
        }
    }

    #pragma unroll
    for (int ns = 0; ns < 4; ++ns) {
        #pragma unroll
        for (int reg = 0; reg < 4; ++reg) {
            int r = row0 + q * 4 + reg;
            if (r < n)
                H[(size_t)r * CH + colh * 64 + ns * 16 + m] = f2bf(acc[ns][reg]);
        }
    }
}

// fused: blocks [0, nbE4): per-edge replicated rank atomic, grid-stride x4
// (long pole, dispatched first); blocks [nbE4, ...): gemm1 (fp32 x).
__global__ __launch_bounds__(TPB, 4)
void k_gemm_rank(const float* __restrict__ X, const short* __restrict__ Wsplit,
                 unsigned short* __restrict__ H, int n,
                 const int* __restrict__ dst, int* __restrict__ counts_rep,
                 int* __restrict__ rank, int E, int nbE4, int Np) {
    int bx = blockIdx.x;
    if (bx < nbE4) {
        int stride = nbE4 * TPB;
        int e = bx * TPB + threadIdx.x;
        #pragma unroll
        for (int it = 0; it < 4; ++it, e += stride) {
            if (e < E) {
                int d = dst[e];
                if ((unsigned)d < (unsigned)n) {
                    int rep = e & (NREP - 1);
                    rank[e] = atomicAdd(&counts_rep[rep * Np + d], 1);
                }
            }
        }
    } else {
        bx -= nbE4;
        int colh = bx & 1;
        gemm_body_f32(X, Wsplit + (size_t)colh * WIMG, H, n, bx >> 1, colh,
                      threadIdx.x);
    }
}

// bf16-input GEMM, W2 hi-only (1 MFMA/frag, 16 KB LDS). (layer 2)
__global__ __launch_bounds__(TPB, 4)
void k_gemm_bf(const unsigned short* __restrict__ X, const short* __restrict__ Wsplit,
               unsigned short* __restrict__ H, int n) {
    __shared__ __align__(16) short sW[4][4][64][8];      // hi-only, 16 KB
    const int tid  = threadIdx.x;
    const int colh = (int)blockIdx.x & 1;
    const int tile = (int)blockIdx.x >> 1;
    {
        const float4* gsrc = (const float4*)(Wsplit + (size_t)colh * WIMG); // hi half
        float4* ldst = (float4*)sW;
        #pragma unroll
        for (int i = 0; i < 4; ++i)
            ldst[i * TPB + tid] = gsrc[i * TPB + tid];
    }
    __syncthreads();

    const int lane = tid & 63;
    const int wv   = tid >> 6;
    const int q    = lane >> 4;
    const int m    = lane & 15;
    const int row0 = tile * 64 + wv * 16;
    if (row0 >= n) return;

    int rrow = row0 + m;
    if (rrow > n - 1) rrow = n - 1;

    const short8* xr8 = (const short8*)(X + (size_t)rrow * CH);
    short8 a[4];
    #pragma unroll
    for (int kt = 0; kt < 4; ++kt) a[kt] = xr8[kt * 4 + q];

    floatx4 acc[4];
    #pragma unroll
    for (int ns = 0; ns < 4; ++ns) acc[ns] = (floatx4){0.f, 0.f, 0.f, 0.f};

    #pragma unroll
    for (int kt = 0; kt < 4; ++kt) {
        #pragma unroll
        for (int ns = 0; ns < 4; ++ns) {
            short8 bh = *(const short8*)&sW[kt][ns][lane][0];
            acc[ns] = __builtin_amdgcn_mfma_f32_16x16x32_bf16(a[kt], bh, acc[ns], 0, 0, 0);
        }
    }

    #pragma unroll
    for (int ns = 0; ns < 4; ++ns) {
        #pragma unroll
        for (int reg = 0; reg < 4; ++reg) {
            int r = row0 + q * 4 + reg;
            if (r < n)
                H[(size_t)r * CH + colh * 64 + ns * 16 + m] = f2bf(acc[ns][reg]);
        }
    }
}

// ---------------------------------------------------------------------------
// scan1: sum 8 replica counts -> counts_tot, replica-exclusive offsets,
// block-local exclusive scan -> row_start; last-finishing block top-scans
// partials into pp_s. Absolute bucket base = row_start[i] + pp_s[i >> 10].
// ---------------------------------------------------------------------------
__global__ __launch_bounds__(SCANB)
void k_scan1(const int* __restrict__ counts_rep, int Np,
             int* __restrict__ counts_tot, int* __restrict__ repoff8,
             int* __restrict__ row_start, int* __restrict__ partials,
             int* __restrict__ pp_s, int* __restrict__ done, int nb, int n) {
    __shared__ int s[SCANB];
    __shared__ int slast;
    int gid = blockIdx.x * SCANB + threadIdx.x;
    int c[NREP];
    int v = 0;
    #pragma unroll
    for (int r = 0; r < NREP; ++r) {
        c[r] = (gid < n) ? counts_rep[r * Np + gid] : 0;
        v += c[r];
    }
    s[threadIdx.x] = v;
    __syncthreads();
    for (int off = 1; off < SCANB; off <<= 1) {
        int t = (threadIdx.x >= off) ? s[threadIdx.x - off] : 0;
        __syncthreads();
        s[threadIdx.x] += t;
        __syncthreads();
    }
    if (gid < n) {
        row_start[gid]  = s[threadIdx.x] - v;   // block-local exclusive
        counts_tot[gid] = v;
        int pre = 0;
        int ro[NREP];
        #pragma unroll
        for (int r = 0; r < NREP; ++r) { ro[r] = pre; pre += c[r]; }
        ((int4*)repoff8)[gid * 2 + 0] = make_int4(ro[0], ro[1], ro[2], ro[3]);
        ((int4*)repoff8)[gid * 2 + 1] = make_int4(ro[4], ro[5], ro[6], ro[7]);
    }
    if (threadIdx.x == SCANB - 1) {
        partials[blockIdx.x] = s[SCANB - 1];
        __threadfence();
        int old = atomicAdd(done, 1);
        slast = (old == nb - 1);
    }
    __syncthreads();
    if (slast && threadIdx.x < 64) {
        int pv = (threadIdx.x < nb) ? atomicAdd(&partials[threadIdx.x], 0) : 0;
        int inc = pv;
        #pragma unroll
        for (int off = 1; off < 64; off <<= 1) {
            int t = __shfl_up(inc, off, 64);
            if ((threadIdx.x & 63) >= off) inc += t;
        }
        if (threadIdx.x < nb) pp_s[threadIdx.x] = inc - pv;
    }
}

// atomic-free fill
__global__ void k_fill(const int* __restrict__ src, const int* __restrict__ dst,
                       const float* __restrict__ ew, const int* __restrict__ row_start,
                       const int* __restrict__ pp_s, const int* __restrict__ repoff8,
                       const int* __restrict__ rank, int2* __restrict__ edges,
                       int E, int n) {
    int e = blockIdx.x * blockDim.x + threadIdx.x;
    if (e >= E) return;
    int s = src[e], d = dst[e];
    if ((unsigned)s >= (unsigned)n || (unsigned)d >= (unsigned)n) return;
    int rep = e & (NREP - 1);
    int base = row_start[d] + pp_s[d >> 10] + repoff8[d * NREP + rep];
    edges[base + rank[e]] = make_int2(s, __float_as_int(ew[e]));
}

// per-node: deg = 1 + sum(raw ew over bucket); dinv = rsqrt(deg)
__global__ void k_deg(const int* __restrict__ row_start, const int* __restrict__ pp_s,
                      const int* __restrict__ counts, const int2* __restrict__ edges,
                      float* __restrict__ dinv, int n) {
    int i = blockIdx.x * blockDim.x + threadIdx.x;
    if (i >= n) return;
    int j = row_start[i] + pp_s[i >> 10], end = j + counts[i];
    float sum = 1.0f;
    for (; j < end; ++j) sum += __int_as_float(edges[j].y);
    dinv[i] = rsqrtf(sum);
}

// ---------------------------------------------------------------------------
// aggregate core, 16 lanes/node, 8 channels/lane (short8 16B gathers):
//   o = h[node]*di^2 + bias + di*sum(w'*h[src])
// FIXUP: w' = raw_ew*dinv[src], written back by lane tx==0.
// ---------------------------------------------------------------------------
template<int FIXUP>
static __device__ __forceinline__ float8 agg_node8(
        const short8* __restrict__ h8, int2* __restrict__ edges,
        const float* __restrict__ dinv, const float8 b, int node, int tx,
        const int* __restrict__ row_start, const int* __restrict__ pp_s,
        const int* __restrict__ counts) {
    float di = dinv[node];
    float8 hv = bf8_to_f8(h8[(size_t)node * 16 + tx]);
    float8 acc;
    #pragma unroll
    for (int i = 0; i < 8; ++i) acc[i] = 0.f;

    int j   = row_start[node] + pp_s[node >> 10];
    int end = j + counts[node];

    for (; j + 8 <= end; j += 8) {
        int2 e[8];
        #pragma unroll
        for (int i = 0; i < 8; ++i) e[i] = edges[j + i];
        short8 g[8];
        #pragma unroll
        for (int i = 0; i < 8; ++i) g[i] = h8[(size_t)e[i].x * 16 + tx];
        float w[8];
        #pragma unroll
        for (int i = 0; i < 8; ++i) {
            w[i] = __int_as_float(e[i].y);
            if (FIXUP) w[i] *= dinv[e[i].x];
        }
        if (FIXUP && tx == 0) {
            #pragma unroll
            for (int i = 0; i < 8; ++i) edges[j + i].y = __float_as_int(w[i]);
        }
        #pragma unroll
        for (int i = 0; i < 8; ++i) {
            float8 gf = bf8_to_f8(g[i]);
            #pragma unroll
            for (int c = 0; c < 8; ++c) acc[c] += gf[c] * w[i];
        }
    }
    if (j + 4 <= end) {
        int2 e[4];
        #pragma unroll
        for (int i = 0; i < 4; ++i) e[i] = edges[j + i];
        short8 g[4];
        #pragma unroll
        for (int i = 0; i < 4; ++i) g[i] = h8[(size_t)e[i].x * 16 + tx];
        float w[4];
        #pragma unroll
        for (int i = 0; i < 4; ++i) {
            w[i] = __int_as_float(e[i].y);
            if (FIXUP) w[i] *= dinv[e[i].x];
        }
        if (FIXUP && tx == 0) {
            #pragma unroll
            for (int i = 0; i < 4; ++i) edges[j + i].y = __float_as_int(w[i]);
        }
        #pragma unroll
        for (int i = 0; i < 4; ++i) {
            float8 gf = bf8_to_f8(g[i]);
            #pragma unroll
            for (int c = 0; c < 8; ++c) acc[c] += gf[c] * w[i];
        }
        j += 4;
    }
    for (; j < end; ++j) {
        int2 e0 = edges[j];
        float w0 = __int_as_float(e0.y);
        if (FIXUP) w0 *= dinv[e0.x];
        if (FIXUP && tx == 0) edges[j].y = __float_as_int(w0);
        float8 gf = bf8_to_f8(h8[(size_t)e0.x * 16 + tx]);
        #pragma unroll
        for (int c = 0; c < 8; ++c) acc[c] += gf[c] * w0;
    }

    float sc = di * di;
    float8 o;
    #pragma unroll
    for (int c = 0; c < 8; ++c) o[c] = hv[c] * sc + b[c] + di * acc[c];
    return o;
}

// agg1: o1 = relu(agg(h)) in bf16; computes+stores w' (FIXUP). 16 nodes/block.
__global__ __launch_bounds__(TPB)
void k_aggregate1(const unsigned short* __restrict__ h,
                  const int* __restrict__ row_start, const int* __restrict__ pp_s,
                  const int* __restrict__ counts, int2* __restrict__ edges,
                  const float* __restrict__ dinv, const float* __restrict__ bias,
                  unsigned short* __restrict__ out, int n) {
    int t = blockIdx.x * blockDim.x + threadIdx.x;
    int node = t >> 4;
    if (node >= n) return;
    int tx = t & 15;
    float8 b;
    #pragma unroll
    for (int c = 0; c < 8; ++c) b[c] = bias[tx * 8 + c];
    float8 o = agg_node8<1>((const short8*)h, edges, dinv, b, node, tx,
                            row_start, pp_s, counts);
    short8 u;
    #pragma unroll
    for (int c = 0; c < 8; ++c) u[c] = (short)f2bf(fmaxf(o[c], 0.f));
    ((short8*)out)[(size_t)node * 16 + tx] = u;
}

// agg2: out = relu(agg(h2)) in fp32. 16 nodes/block.
__global__ __launch_bounds__(TPB)
void k_aggregate2(const unsigned short* __restrict__ h,
                  const int* __restrict__ row_start, const int* __restrict__ pp_s,
                  const int* __restrict__ counts, int2* __restrict__ edges,
                  const float* __restrict__ dinv, const float* __restrict__ bias,
                  float* __restrict__ out, int n) {
    int t = blockIdx.x * blockDim.x + threadIdx.x;
    int node = t >> 4;
    if (node >= n) return;
    int tx = t & 15;
    float8 b;
    #pragma unroll
    for (int c = 0; c < 8; ++c) b[c] = bias[tx * 8 + c];
    float8 o = agg_node8<0>((const short8*)h, edges, dinv, b, node, tx,
                            row_start, pp_s, counts);
    float4 lo = make_float4(fmaxf(o[0], 0.f), fmaxf(o[1], 0.f),
                            fmaxf(o[2], 0.f), fmaxf(o[3], 0.f));
    float4 hi = make_float4(fmaxf(o[4], 0.f), fmaxf(o[5], 0.f),
                            fmaxf(o[6], 0.f), fmaxf(o[7], 0.f));
    ((float4*)out)[(size_t)node * CH4 + tx * 2 + 0] = lo;
    ((float4*)out)[(size_t)node * CH4 + tx * 2 + 1] = hi;
}

// ---------------------------------------------------------------------------
extern "C" void kernel_launch(void* const* d_in, const int* in_sizes, int n_in,
                              void* d_out, int out_size, void* d_ws, size_t ws_size,
                              hipStream_t stream) {
    const float* x  = (const float*)d_in[0];   // [N,128]
    const int*   ei = (const int*)d_in[1];     // [2,E]
    const float* ew = (const float*)d_in[2];   // [E]
    const float* W1 = (const float*)d_in[3];
    const float* b1 = (const float*)d_in[4];
    const float* W2 = (const float*)d_in[5];
    const float* b2 = (const float*)d_in[6];
    float* out = (float*)d_out;                // [N,128]

    const int N = in_sizes[0] / CH;
    const int E = in_sizes[2];
    const int* src = ei;
    const int* dst = ei + E;

    // workspace layout (16B-aligned)
    size_t Np = ((size_t)N + 255) & ~(size_t)255;
    size_t Ep = ((size_t)E + 63) & ~(size_t)63;
    float* ws          = (float*)d_ws;
    float* dinv        = ws;                                // Np floats
    unsigned short* h  = (unsigned short*)(dinv + Np);      // N*CH bf16 (gemm1 out)
    unsigned short* o1 = h + (size_t)N * CH;                // N*CH bf16 (agg1 out)
    unsigned short* h2 = o1 + (size_t)N * CH;               // N*CH bf16 (gemm2 out)
    // ---- contiguous zero region ----
    int*   counts_rep  = (int*)(h2 + (size_t)N * CH);       // NREP*Np ints
    int*   done        = counts_rep + NREP * Np;            // 64 ints (1 used)
    size_t zero_bytes  = (size_t)NREP * Np * 4 + 256;
    // ---- rest ----
    int*  counts_tot   = done + 64;                         // Np ints
    int*  row_start    = counts_tot + Np;                   // Np ints
    int*  repoff8      = row_start + Np;                    // NREP*Np ints
    int*  rank         = repoff8 + NREP * Np;               // Ep ints
    int*  partials     = rank + Ep;                         // 64 ints
    int*  pp_s         = partials + 64;                     // 64 ints
    int2* edges        = (int2*)(pp_s + 64);                // E int2
    short* Wsplit      = (short*)(edges + E);               // 4*WIMG shorts

    const int nbN    = (N + TPB - 1) / TPB;
    const int nbE    = (E + TPB - 1) / TPB;
    const int nbE4   = (E + TPB * 4 - 1) / (TPB * 4);
    const int nbAgg  = (int)(((size_t)N * 16 + TPB - 1) / TPB);
    const int nbScan = (N + SCANB - 1) / SCANB;     // 49 <= 64
    const int nbGemm2 = 2 * ((N + 63) / 64);
    const int nbPrep  = (2 * CH * CH + TPB - 1) / TPB;

    // ---- prep: zero counters+done, split W ----
    hipMemsetAsync(counts_rep, 0, zero_bytes, stream);
    k_prep     <<<nbPrep, TPB, 0, stream>>>(W1, W2, Wsplit);

    // ---- fused: replicated rank pass (grid-stride x4) | gemm1 ----
    k_gemm_rank<<<nbE4 + nbGemm2, TPB, 0, stream>>>(x, Wsplit, h, N, dst,
                                                    counts_rep, rank, E, nbE4, (int)Np);
    // ---- CSR finalize ----
    k_scan1    <<<nbScan, SCANB, 0, stream>>>(counts_rep, (int)Np, counts_tot,
                                              repoff8, row_start, partials,
                                              pp_s, done, nbScan, N);
    k_fill     <<<nbE, TPB, 0, stream>>>(src, dst, ew, row_start, pp_s, repoff8,
                                         rank, edges, E, N);
    k_deg      <<<nbN, TPB, 0, stream>>>(row_start, pp_s, counts_tot, edges,
                                         dinv, N);

    // ---- layer 1 aggregate -> o1 (bf16, ReLU); stores w' ----
    k_aggregate1<<<nbAgg, TPB, 0, stream>>>(h, row_start, pp_s, counts_tot,
                                            edges, dinv, b1, o1, N);
    // ---- layer 2 ----
    k_gemm_bf   <<<nbGemm2, TPB, 0, stream>>>(o1, Wsplit + 2 * (size_t)WIMG, h2, N);
    k_aggregate2<<<nbAgg, TPB, 0, stream>>>(h2, row_start, pp_s, counts_tot,
                                            edges, dinv, b2, out, N);
}

// Round 14
// 212.449 us; speedup vs baseline: 1.1831x; 1.0153x over previous
//
#include <hip/hip_runtime.h>
#include <math.h>

// GCN 2-layer forward on MI355X — round 14:
//  * algebraic refactor: h~ = h*dinv[row] (scaled once, coalesced, in k_deg_scale)
//    => aggregates need NO dinv[src] gathers / FIXUP writebacks:
//    out[d] = di*( h~[d] + sum_e ew*h~[src] ) + b
//  * gemm_bf scales its output rows by dinv (free epilogue) for layer 2
//  * memset folded into k_prep (one fewer dispatch)
#define CH   128
#define CH4  32
#define TPB  256
#define SCANB 1024
#define WIMG 16384       // shorts per (layer,colh) fragment image (32 KB)
#define NREP 8

typedef __attribute__((ext_vector_type(8))) short short8;   // 8 bf16 (4 VGPRs)
typedef __attribute__((ext_vector_type(4))) float floatx4;  // MFMA acc
typedef __attribute__((ext_vector_type(8))) float float8;

static __device__ __forceinline__ unsigned short f2bf(float f) {
    unsigned u = __float_as_uint(f);
    return (unsigned short)((u + 0x7fffu + ((u >> 16) & 1u)) >> 16);
}
static __device__ __forceinline__ float bf2f(unsigned short s) {
    return __uint_as_float(((unsigned)s) << 16);
}
static __device__ __forceinline__ float8 bf8_to_f8(short8 u) {
    float8 f;
    #pragma unroll
    for (int i = 0; i < 8; ++i) f[i] = bf2f((unsigned short)u[i]);
    return f;
}

// ---------------------------------------------------------------------------
// k_prep: blocks [0,nbPrep): split W1,W2 into bf16 hi/lo fragment images;
// blocks [nbPrep,..): zero counts_rep + done (replaces hipMemsetAsync).
// ---------------------------------------------------------------------------
__global__ void k_prep(const float* __restrict__ W1, const float* __restrict__ W2,
                       short* __restrict__ Wsplit, float4* __restrict__ zbase,
                       int nzero4, int nbPrep) {
    int bx = blockIdx.x;
    if (bx >= nbPrep) {
        int i = (bx - nbPrep) * TPB + threadIdx.x;
        if (i < nzero4) zbase[i] = make_float4(0.f, 0.f, 0.f, 0.f);
        return;
    }
    int i = bx * TPB + threadIdx.x;   // over 2*128*128
    if (i >= 2 * CH * CH) return;
    int layer = i >> 14;
    int idx   = i & 16383;
    int k = idx >> 7, c = idx & 127;
    float w = (layer ? W2 : W1)[k * CH + c];
    unsigned short hi = f2bf(w);
    unsigned short lo = f2bf(w - bf2f(hi));
    int colh = c >> 6, nn = c & 63;
    int kt = k >> 5, q = (k & 31) >> 3, j = k & 7;
    int ns = nn >> 4, ln = q * 16 + (nn & 15);
    size_t base = (size_t)(layer * 2 + colh) * WIMG;
    size_t off  = ((size_t)(kt * 4 + ns) * 64 + ln) * 8 + j;
    Wsplit[base + off]        = (short)hi;   // hi: first 16 KB of image
    Wsplit[base + 8192 + off] = (short)lo;   // lo: second 16 KB
}

// ---------------------------------------------------------------------------
// fp32-input MFMA GEMM body (3-term Markidis split), bf16 output. (layer 1)
// A: m=lane&15, k=(lane>>4)*8+j ; B mirrored ; D: col=lane&15, row=(lane>>4)*4+reg
// ---------------------------------------------------------------------------
static __device__ __forceinline__ void gemm_body_f32(
        const float* __restrict__ X, const short* __restrict__ Wfrag,
        unsigned short* __restrict__ H, int n, int tile, int colh, int tid) {
    __shared__ __align__(16) short sW[2][4][4][64][8];   // 32 KB (hi+lo)
    {
        const float4* gsrc = (const float4*)Wfrag;
        float4* ldst = (float4*)sW;
        #pragma unroll
        for (int i = 0; i < 8; ++i)
            ldst[i * TPB + tid] = gsrc[i * TPB + tid];
    }
    __syncthreads();

    const int lane = tid & 63;
    const int wv   = tid >> 6;
    const int q    = lane >> 4;
    const int m    = lane & 15;
    const int row0 = tile * 64 + wv * 16;
    if (row0 >= n) return;

    int rrow = row0 + m;
    if (rrow > n - 1) rrow = n - 1;

    const float4* xr = (const float4*)(X + (size_t)rrow * CH);
    float4 xa[4][2];
    #pragma unroll
    for (int kt = 0; kt < 4; ++kt) {
        xa[kt][0] = xr[kt * 8 + q * 2 + 0];
        xa[kt][1] = xr[kt * 8 + q * 2 + 1];
    }

    floatx4 acc[4];
    #pragma unroll
    for (int ns = 0; ns < 4; ++ns) acc[ns] = (floatx4){0.f, 0.f, 0.f, 0.f};

    #pragma unroll
    for (int kt = 0; kt < 4; ++kt) {
        float xf[8] = { xa[kt][0].x, xa[kt][0].y, xa[kt][0].z, xa[kt][0].w,
                        xa[kt][1].x, xa[kt][1].y, xa[kt][1].z, xa[kt][1].w };
        short8 ah, al;
        #pragma unroll
        for (int j = 0; j < 8; ++j) {
            float v = xf[j];
            unsigned short h = f2bf(v);
            ah[j] = (short)h;
            al[j] = (short)f2bf(v - bf2f(h));
        }
        #pragma unroll
        for (int ns = 0; ns < 4; ++ns) {
            short8 bh = *(const short8*)&sW[0][kt][ns][lane][0];
            short8 bl = *(const short8*)&sW[1][kt][ns][lane][0];
            acc[ns] = __builtin_amdgcn_mfma_f32_16x16x32_bf16(ah, bh, acc[ns], 0, 0, 0);
            acc[ns] = __builtin_amdgcn_mfma_f32_16x16x32_bf16(al, bh, acc[ns], 0, 0, 0);
            acc[ns] = __builtin_amdgcn_mfma_f32_16x16x32_bf16(ah, bl, acc[ns], 0, 0, 0);
        }
    }

    #pragma unroll
    for (int ns = 0; ns < 4; ++ns) {
        #pragma unroll
        for (int reg = 0; reg < 4; ++reg) {
            int r = row0 + q * 4 + reg;
            if (r < n)
                H[(size_t)r * CH + colh * 64 + ns * 16 + m] = f2bf(acc[ns][reg]);
        }
    }
}

// fused: blocks [0, nbE4): per-edge replicated rank atomic, grid-stride x4
// (long pole, dispatched first); blocks [nbE4, ...): gemm1 (fp32 x).
__global__ __launch_bounds__(TPB, 4)
void k_gemm_rank(const float* __restrict__ X, const short* __restrict__ Wsplit,
                 unsigned short* __restrict__ H, int n,
                 const int* __restrict__ dst, int* __restrict__ counts_rep,
                 int* __restrict__ rank, int E, int nbE4, int Np) {
    int bx = blockIdx.x;
    if (bx < nbE4) {
        int stride = nbE4 * TPB;
        int e = bx * TPB + threadIdx.x;
        #pragma unroll
        for (int it = 0; it < 4; ++it, e += stride) {
            if (e < E) {
                int d = dst[e];
                if ((unsigned)d < (unsigned)n) {
                    int rep = e & (NREP - 1);
                    rank[e] = atomicAdd(&counts_rep[rep * Np + d], 1);
                }
            }
        }
    } else {
        bx -= nbE4;
        int colh = bx & 1;
        gemm_body_f32(X, Wsplit + (size_t)colh * WIMG, H, n, bx >> 1, colh,
                      threadIdx.x);
    }
}

// bf16-input GEMM, W2 hi-only (1 MFMA/frag, 16 KB LDS); output rows scaled
// by dinv[row] (layer-2 pre-scaling for the simplified aggregate).
__global__ __launch_bounds__(TPB, 4)
void k_gemm_bf(const unsigned short* __restrict__ X, const short* __restrict__ Wsplit,
               const float* __restrict__ dinv, unsigned short* __restrict__ H, int n) {
    __shared__ __align__(16) short sW[4][4][64][8];      // hi-only, 16 KB
    const int tid  = threadIdx.x;
    const int colh = (int)blockIdx.x & 1;
    const int tile = (int)blockIdx.x >> 1;
    {
        const float4* gsrc = (const float4*)(Wsplit + (size_t)colh * WIMG); // hi half
        float4* ldst = (float4*)sW;
        #pragma unroll
        for (int i = 0; i < 4; ++i)
            ldst[i * TPB + tid] = gsrc[i * TPB + tid];
    }
    __syncthreads();

    const int lane = tid & 63;
    const int wv   = tid >> 6;
    const int q    = lane >> 4;
    const int m    = lane & 15;
    const int row0 = tile * 64 + wv * 16;
    if (row0 >= n) return;

    int rrow = row0 + m;
    if (rrow > n - 1) rrow = n - 1;

    const short8* xr8 = (const short8*)(X + (size_t)rrow * CH);
    short8 a[4];
    #pragma unroll
    for (int kt = 0; kt < 4; ++kt) a[kt] = xr8[kt * 4 + q];

    floatx4 acc[4];
    #pragma unroll
    for (int ns = 0; ns < 4; ++ns) acc[ns] = (floatx4){0.f, 0.f, 0.f, 0.f};

    #pragma unroll
    for (int kt = 0; kt < 4; ++kt) {
        #pragma unroll
        for (int ns = 0; ns < 4; ++ns) {
            short8 bh = *(const short8*)&sW[kt][ns][lane][0];
            acc[ns] = __builtin_amdgcn_mfma_f32_16x16x32_bf16(a[kt], bh, acc[ns], 0, 0, 0);
        }
    }

    float dr[4];
    #pragma unroll
    for (int reg = 0; reg < 4; ++reg) {
        int r = row0 + q * 4 + reg;
        dr[reg] = (r < n) ? dinv[r] : 0.f;
    }
    #pragma unroll
    for (int ns = 0; ns < 4; ++ns) {
        #pragma unroll
        for (int reg = 0; reg < 4; ++reg) {
            int r = row0 + q * 4 + reg;
            if (r < n)
                H[(size_t)r * CH + colh * 64 + ns * 16 + m] =
                    f2bf(acc[ns][reg] * dr[reg]);
        }
    }
}

// ---------------------------------------------------------------------------
// scan1: sum 8 replica counts -> counts_tot, replica-exclusive offsets,
// block-local exclusive scan -> row_start; last-finishing block top-scans
// partials into pp_s. Absolute bucket base = row_start[i] + pp_s[i >> 10].
// ---------------------------------------------------------------------------
__global__ __launch_bounds__(SCANB)
void k_scan1(const int* __restrict__ counts_rep, int Np,
             int* __restrict__ counts_tot, int* __restrict__ repoff8,
             int* __restrict__ row_start, int* __restrict__ partials,
             int* __restrict__ pp_s, int* __restrict__ done, int nb, int n) {
    __shared__ int s[SCANB];
    __shared__ int slast;
    int gid = blockIdx.x * SCANB + threadIdx.x;
    int c[NREP];
    int v = 0;
    #pragma unroll
    for (int r = 0; r < NREP; ++r) {
        c[r] = (gid < n) ? counts_rep[r * Np + gid] : 0;
        v += c[r];
    }
    s[threadIdx.x] = v;
    __syncthreads();
    for (int off = 1; off < SCANB; off <<= 1) {
        int t = (threadIdx.x >= off) ? s[threadIdx.x - off] : 0;
        __syncthreads();
        s[threadIdx.x] += t;
        __syncthreads();
    }
    if (gid < n) {
        row_start[gid]  = s[threadIdx.x] - v;   // block-local exclusive
        counts_tot[gid] = v;
        int pre = 0;
        int ro[NREP];
        #pragma unroll
        for (int r = 0; r < NREP; ++r) { ro[r] = pre; pre += c[r]; }
        ((int4*)repoff8)[gid * 2 + 0] = make_int4(ro[0], ro[1], ro[2], ro[3]);
        ((int4*)repoff8)[gid * 2 + 1] = make_int4(ro[4], ro[5], ro[6], ro[7]);
    }
    if (threadIdx.x == SCANB - 1) {
        partials[blockIdx.x] = s[SCANB - 1];
        __threadfence();
        int old = atomicAdd(done, 1);
        slast = (old == nb - 1);
    }
    __syncthreads();
    if (slast && threadIdx.x < 64) {
        int pv = (threadIdx.x < nb) ? atomicAdd(&partials[threadIdx.x], 0) : 0;
        int inc = pv;
        #pragma unroll
        for (int off = 1; off < 64; off <<= 1) {
            int t = __shfl_up(inc, off, 64);
            if ((threadIdx.x & 63) >= off) inc += t;
        }
        if (threadIdx.x < nb) pp_s[threadIdx.x] = inc - pv;
    }
}

// atomic-free fill: edges hold {src, RAW ew} forever (read-only afterwards)
__global__ void k_fill(const int* __restrict__ src, const int* __restrict__ dst,
                       const float* __restrict__ ew, const int* __restrict__ row_start,
                       const int* __restrict__ pp_s, const int* __restrict__ repoff8,
                       const int* __restrict__ rank, int2* __restrict__ edges,
                       int E, int n) {
    int e = blockIdx.x * blockDim.x + threadIdx.x;
    if (e >= E) return;
    int s = src[e], d = dst[e];
    if ((unsigned)s >= (unsigned)n || (unsigned)d >= (unsigned)n) return;
    int rep = e & (NREP - 1);
    int base = row_start[d] + pp_s[d >> 10] + repoff8[d * NREP + rep];
    edges[base + rank[e]] = make_int2(s, __float_as_int(ew[e]));
}

// ---------------------------------------------------------------------------
// k_deg_scale: 16 lanes/node. deg = 1 + sum(ew over bucket) via shfl-reduce;
// dinv = rsqrt(deg); then scale the node's h row in place: h~ = h * dinv.
// ---------------------------------------------------------------------------
__global__ __launch_bounds__(TPB)
void k_deg_scale(const int* __restrict__ row_start, const int* __restrict__ pp_s,
                 const int* __restrict__ counts, const int2* __restrict__ edges,
                 float* __restrict__ dinv, unsigned short* __restrict__ h, int n) {
    int t = blockIdx.x * blockDim.x + threadIdx.x;
    int node = t >> 4;
    if (node >= n) return;
    int tx = t & 15;
    int j0  = row_start[node] + pp_s[node >> 10];
    int cnt = counts[node];
    float sum = 0.f;
    for (int j = tx; j < cnt; j += 16)
        sum += __int_as_float(edges[j0 + j].y);
    #pragma unroll
    for (int off = 8; off; off >>= 1) sum += __shfl_down(sum, off, 16);
    float di = rsqrtf(1.0f + __shfl(sum, 0, 16));
    if (tx == 0) dinv[node] = di;
    short8* hp = (short8*)h + (size_t)node * 16 + tx;
    short8 v = *hp;
    short8 o;
    #pragma unroll
    for (int c = 0; c < 8; ++c)
        o[c] = (short)f2bf(bf2f((unsigned short)v[c]) * di);
    *hp = o;
}

// ---------------------------------------------------------------------------
// simplified aggregate core over pre-scaled h~ (16 lanes/node, short8 loads):
//   o = di * ( h~[node] + sum_e ew_e * h~[src_e] ) + bias
// ---------------------------------------------------------------------------
static __device__ __forceinline__ float8 agg_node8(
        const short8* __restrict__ h8, const int2* __restrict__ edges,
        float di, const float8 b, int node, int tx,
        const int* __restrict__ row_start, const int* __restrict__ pp_s,
        const int* __restrict__ counts) {
    float8 hv = bf8_to_f8(h8[(size_t)node * 16 + tx]);
    float8 acc;
    #pragma unroll
    for (int i = 0; i < 8; ++i) acc[i] = 0.f;

    int j   = row_start[node] + pp_s[node >> 10];
    int end = j + counts[node];

    for (; j + 8 <= end; j += 8) {
        int2 e[8];
        #pragma unroll
        for (int i = 0; i < 8; ++i) e[i] = edges[j + i];
        short8 g[8];
        #pragma unroll
        for (int i = 0; i < 8; ++i) g[i] = h8[(size_t)e[i].x * 16 + tx];
        #pragma unroll
        for (int i = 0; i < 8; ++i) {
            float w = __int_as_float(e[i].y);
            float8 gf = bf8_to_f8(g[i]);
            #pragma unroll
            for (int c = 0; c < 8; ++c) acc[c] += gf[c] * w;
        }
    }
    if (j + 4 <= end) {
        int2 e[4];
        #pragma unroll
        for (int i = 0; i < 4; ++i) e[i] = edges[j + i];
        short8 g[4];
        #pragma unroll
        for (int i = 0; i < 4; ++i) g[i] = h8[(size_t)e[i].x * 16 + tx];
        #pragma unroll
        for (int i = 0; i < 4; ++i) {
            float w = __int_as_float(e[i].y);
            float8 gf = bf8_to_f8(g[i]);
            #pragma unroll
            for (int c = 0; c < 8; ++c) acc[c] += gf[c] * w;
        }
        j += 4;
    }
    for (; j < end; ++j) {
        int2 e0 = edges[j];
        float w0 = __int_as_float(e0.y);
        float8 gf = bf8_to_f8(h8[(size_t)e0.x * 16 + tx]);
        #pragma unroll
        for (int c = 0; c < 8; ++c) acc[c] += gf[c] * w0;
    }

    float8 o;
    #pragma unroll
    for (int c = 0; c < 8; ++c) o[c] = di * (hv[c] + acc[c]) + b[c];
    return o;
}

// agg1: o1 = relu(agg(h~)) in bf16. 16 nodes/block of 256.
__global__ __launch_bounds__(TPB)
void k_aggregate1(const unsigned short* __restrict__ h,
                  const int* __restrict__ row_start, const int* __restrict__ pp_s,
                  const int* __restrict__ counts, const int2* __restrict__ edges,
                  const float* __restrict__ dinv, const float* __restrict__ bias,
                  unsigned short* __restrict__ out, int n) {
    int t = blockIdx.x * blockDim.x + threadIdx.x;
    int node = t >> 4;
    if (node >= n) return;
    int tx = t & 15;
    float8 b;
    #pragma unroll
    for (int c = 0; c < 8; ++c) b[c] = bias[tx * 8 + c];
    float8 o = agg_node8((const short8*)h, edges, dinv[node], b, node, tx,
                         row_start, pp_s, counts);
    short8 u;
    #pragma unroll
    for (int c = 0; c < 8; ++c) u[c] = (short)f2bf(fmaxf(o[c], 0.f));
    ((short8*)out)[(size_t)node * 16 + tx] = u;
}

// agg2: out = relu(agg(h2~)) in fp32.
__global__ __launch_bounds__(TPB)
void k_aggregate2(const unsigned short* __restrict__ h,
                  const int* __restrict__ row_start, const int* __restrict__ pp_s,
                  const int* __restrict__ counts, const int2* __restrict__ edges,
                  const float* __restrict__ dinv, const float* __restrict__ bias,
                  float* __restrict__ out, int n) {
    int t = blockIdx.x * blockDim.x + threadIdx.x;
    int node = t >> 4;
    if (node >= n) return;
    int tx = t & 15;
    float8 b;
    #pragma unroll
    for (int c = 0; c < 8; ++c) b[c] = bias[tx * 8 + c];
    float8 o = agg_node8((const short8*)h, edges, dinv[node], b, node, tx,
                         row_start, pp_s, counts);
    float4 lo = make_float4(fmaxf(o[0], 0.f), fmaxf(o[1], 0.f),
                            fmaxf(o[2], 0.f), fmaxf(o[3], 0.f));
    float4 hi = make_float4(fmaxf(o[4], 0.f), fmaxf(o[5], 0.f),
                            fmaxf(o[6], 0.f), fmaxf(o[7], 0.f));
    ((float4*)out)[(size_t)node * CH4 + tx * 2 + 0] = lo;
    ((float4*)out)[(size_t)node * CH4 + tx * 2 + 1] = hi;
}

// ---------------------------------------------------------------------------
extern "C" void kernel_launch(void* const* d_in, const int* in_sizes, int n_in,
                              void* d_out, int out_size, void* d_ws, size_t ws_size,
                              hipStream_t stream) {
    const float* x  = (const float*)d_in[0];   // [N,128]
    const int*   ei = (const int*)d_in[1];     // [2,E]
    const float* ew = (const float*)d_in[2];   // [E]
    const float* W1 = (const float*)d_in[3];
    const float* b1 = (const float*)d_in[4];
    const float* W2 = (const float*)d_in[5];
    const float* b2 = (const float*)d_in[6];
    float* out = (float*)d_out;                // [N,128]

    const int N = in_sizes[0] / CH;
    const int E = in_sizes[2];
    const int* src = ei;
    const int* dst = ei + E;

    // workspace layout (16B-aligned)
    size_t Np = ((size_t)N + 255) & ~(size_t)255;
    size_t Ep = ((size_t)E + 63) & ~(size_t)63;
    float* ws          = (float*)d_ws;
    float* dinv        = ws;                                // Np floats
    unsigned short* h  = (unsigned short*)(dinv + Np);      // N*CH bf16 (gemm1 out)
    unsigned short* o1 = h + (size_t)N * CH;                // N*CH bf16 (agg1 out)
    unsigned short* h2 = o1 + (size_t)N * CH;               // N*CH bf16 (gemm2 out)
    // ---- contiguous zero region ----
    int*   counts_rep  = (int*)(h2 + (size_t)N * CH);       // NREP*Np ints
    int*   done        = counts_rep + NREP * Np;            // 64 ints (1 used)
    int    nzero4      = (int)((NREP * Np + 64) / 4);
    // ---- rest ----
    int*  counts_tot   = done + 64;                         // Np ints
    int*  row_start    = counts_tot + Np;                   // Np ints
    int*  repoff8      = row_start + Np;                    // NREP*Np ints
    int*  rank         = repoff8 + NREP * Np;               // Ep ints
    int*  partials     = rank + Ep;                         // 64 ints
    int*  pp_s         = partials + 64;                     // 64 ints
    int2* edges        = (int2*)(pp_s + 64);                // E int2
    short* Wsplit      = (short*)(edges + E);               // 4*WIMG shorts

    const int nbE    = (E + TPB - 1) / TPB;
    const int nbE4   = (E + TPB * 4 - 1) / (TPB * 4);
    const int nbAgg  = (int)(((size_t)N * 16 + TPB - 1) / TPB);
    const int nbScan = (N + SCANB - 1) / SCANB;     // 49 <= 64
    const int nbGemm2 = 2 * ((N + 63) / 64);
    const int nbPrep  = (2 * CH * CH + TPB - 1) / TPB;
    const int nbZero  = (nzero4 + TPB - 1) / TPB;

    // ---- prep: split W + zero counters (fused) ----
    k_prep     <<<nbPrep + nbZero, TPB, 0, stream>>>(W1, W2, Wsplit,
                                                     (float4*)counts_rep,
                                                     nzero4, nbPrep);

    // ---- fused: replicated rank pass (grid-stride x4) | gemm1 ----
    k_gemm_rank<<<nbE4 + nbGemm2, TPB, 0, stream>>>(x, Wsplit, h, N, dst,
                                                    counts_rep, rank, E, nbE4, (int)Np);
    // ---- CSR finalize ----
    k_scan1    <<<nbScan, SCANB, 0, stream>>>(counts_rep, (int)Np, counts_tot,
                                              repoff8, row_start, partials,
                                              pp_s, done, nbScan, N);
    k_fill     <<<nbE, TPB, 0, stream>>>(src, dst, ew, row_start, pp_s, repoff8,
                                         rank, edges, E, N);
    // ---- dinv + in-place scale h -> h~ ----
    k_deg_scale<<<nbAgg, TPB, 0, stream>>>(row_start, pp_s, counts_tot, edges,
                                           dinv, h, N);

    // ---- layer 1 aggregate -> o1 (bf16, ReLU) ----
    k_aggregate1<<<nbAgg, TPB, 0, stream>>>(h, row_start, pp_s, counts_tot,
                                            edges, dinv, b1, o1, N);
    // ---- layer 2: gemm (rows pre-scaled by dinv) + aggregate ----
    k_gemm_bf   <<<nbGemm2, TPB, 0, stream>>>(o1, Wsplit + 2 * (size_t)WIMG,
                                              dinv, h2, N);
    k_aggregate2<<<nbAgg, TPB, 0, stream>>>(h2, row_start, pp_s, counts_tot,
                                            edges, dinv, b2, out, N);
}